// Round 8
// baseline (346.871 us; speedup 1.0000x reference)
//
#include <hip/hip_runtime.h>
#include <math.h>

#define NODES 64
#define NSTEPS 64
#define EPG 1024
#define NTHREADS 512
#define NBLOCKS 256

typedef _Float16 f16;
typedef f16 f16x8 __attribute__((ext_vector_type(8)));
typedef f16 f16x4 __attribute__((ext_vector_type(4)));
typedef float f32x4 __attribute__((ext_vector_type(4)));

// ---- LDS regions (byte offsets) ----
#define R_WZ    0        // setup: Wt f16 [64 f][304 K] = 38912 ; scan: Zt f16 [64 t][64 n][4] = 32768 ; ph3 overlay
#define R_M     38912    // M1 @ +0, M2 @ +9216, M3 @ +18432  ([64][72] f16, row-major)
#define R_MT    66560    // M1T @ +0, M2T @ +9216
#define R_H     84992    // h frag-linear, 2 buffers x 8192 B:  [4 nt x 2 ch][64 slot][16 B]
#define R_XT    101376   // X^T [64][72] f16 (setup only)
#define R_LGF   110592   // f32 [64][64] Laplacian scratch
#define R_DEG   126976
#define R_DINV  127232
#define R_BSUM  127488
#define R_LOGIT 127744
#define SMEM_BYTES 128000

__device__ __forceinline__ f32x4 mfma16(f16x8 a, f16x8 b, f32x4 c) {
  return __builtin_amdgcn_mfma_f32_16x16x32_f16(a, b, c, 0, 0, 0);
}
__device__ __forceinline__ f32x4 k16(f16x4 a, f16x4 b, f32x4 c) {
  return __builtin_amdgcn_mfma_f32_16x16x16f16(a, b, c, 0, 0, 0);
}

// setup: D[i][j] = sum_m A[rb*16+i][m] * B[cb*16+j][m], strides 72
__device__ __forceinline__ f32x4 mm64t(const f16* __restrict__ A, const f16* __restrict__ B,
                                       int rb, int cb, int lrow, int lk)
{
  f32x4 d = (f32x4){0.f, 0.f, 0.f, 0.f};
#pragma unroll
  for (int ch = 0; ch < 2; ++ch) {
    const f16x8 a = *(const f16x8*)(A + (rb * 16 + lrow) * 72 + ch * 32 + lk * 8);
    const f16x8 b = *(const f16x8*)(B + (cb * 16 + lrow) * 72 + ch * 32 + lk * 8);
    d = mfma16(a, b, d);
  }
  return d;
}

// fp32 4x4-tile matmul (phase 3)
template<int K>
__device__ __forceinline__ void mm4x4_acc(float acc[4][4],
                                          const float* __restrict__ A, int lda, int arow,
                                          const float* __restrict__ Bm, int ldb, int j4)
{
#pragma unroll 2
  for (int kc = 0; kc < K; kc += 4) {
    float av[4][4];
    float bv[4][4];
#pragma unroll
    for (int rr = 0; rr < 4; ++rr) {
      const float4 t = *(const float4*)(A + (arow + rr) * lda + kc);
      av[rr][0] = t.x; av[rr][1] = t.y; av[rr][2] = t.z; av[rr][3] = t.w;
    }
#pragma unroll
    for (int kk = 0; kk < 4; ++kk) {
      const float4 t = *(const float4*)(Bm + (kc + kk) * ldb + j4);
      bv[kk][0] = t.x; bv[kk][1] = t.y; bv[kk][2] = t.z; bv[kk][3] = t.w;
    }
#pragma unroll
    for (int rr = 0; rr < 4; ++rr)
#pragma unroll
      for (int cc = 0; cc < 4; ++cc) {
        float s = acc[rr][cc];
#pragma unroll
        for (int kk = 0; kk < 4; ++kk) s += av[rr][kk] * bv[kk][cc];
        acc[rr][cc] = s;
      }
  }
}

__global__ __launch_bounds__(NTHREADS, 2)
void gcrnn_mfma6(const float* __restrict__ x,     // [16384][64]
                 const float* __restrict__ ew,    // [262144]
                 const float* __restrict__ wA,    // [4][1][64]
                 const float* __restrict__ bA,    // [64]
                 const float* __restrict__ wB,    // [4][64][64]
                 const float* __restrict__ bB,    // [64]
                 const float* __restrict__ w1,    // [64][64]
                 const float* __restrict__ b1,    // [64]
                 const float* __restrict__ w2,    // [64][32]
                 const float* __restrict__ b2,    // [32]
                 const float* __restrict__ wfc,   // [2048][4]
                 const float* __restrict__ bfc,   // [4]
                 const int* __restrict__ esrc,
                 const int* __restrict__ edst,
                 float* __restrict__ out)         // [256][4]
{
  __shared__ __align__(16) char smem[SMEM_BYTES];

  f16*   sWt   = (f16*)(smem + R_WZ);
  f16*   sZt   = (f16*)(smem + R_WZ);
  f16*   sM1   = (f16*)(smem + R_M);
  f16*   sM2   = (f16*)(smem + R_M + 9216);
  f16*   sM3   = (f16*)(smem + R_M + 18432);
  f16*   sM1T  = (f16*)(smem + R_MT);
  f16*   sM2T  = (f16*)(smem + R_MT + 9216);
  f16*   sXT   = (f16*)(smem + R_XT);
  float* sLgF  = (float*)(smem + R_LGF);
  float* sDeg  = (float*)(smem + R_DEG);
  float* sDinv = (float*)(smem + R_DINV);
  float* sBsum = (float*)(smem + R_BSUM);
  float* sLogit= (float*)(smem + R_LOGIT);

  const int b = blockIdx.x, tid = threadIdx.x;
  const int gbase = b * NODES, ebase = b * EPG;
  const int wid = tid >> 6, lane = tid & 63;
  const int lrow = lane & 15, lk = lane >> 4;
  const int strip = wid & 3;          // f-strip (output feature block)
  const int nhalf = wid >> 2;         // n-half: out-tiles {2*nhalf, 2*nhalf+1}

  // ---------------- Setup stage 1: stage Wt, XT; zero LGF ----------------
  for (int idx = tid; idx < 4096; idx += NTHREADS) sLgF[idx] = 0.f;
  if (tid < 64) { sDeg[tid] = 0.f; sBsum[tid] = bA[tid] + bB[tid]; }
  // Wt [f][K=304]: 0..255 = wB (K=64k+c_in, value wB[k][c_in][f]), 256..259 = wA, 260..303 = 0
  for (int idx = tid; idx < 64 * 260; idx += NTHREADS) {
    const int k = idx >> 6, f = idx & 63;
    const float v = (k < 256) ? wB[(k >> 6) * 4096 + (k & 63) * 64 + f]
                              : wA[(k - 256) * 64 + f];
    sWt[f * 304 + k] = (f16)v;
  }
  for (int idx = tid; idx < 64 * 44; idx += NTHREADS) {
    const int f = idx / 44, j = idx - f * 44;
    sWt[f * 304 + 260 + j] = (f16)0.f;
  }
  // X^T: sXT[t*72+n] = x[gbase+n][t]
  for (int idx = tid; idx < 4096; idx += NTHREADS) {
    const int n = idx >> 6, t = idx & 63;
    sXT[t * 72 + n] = (f16)x[gbase * 64 + idx];
  }
  __syncthreads();

  // ---------------- Laplacian build ----------------
  for (int e = tid; e < EPG; e += NTHREADS)
    atomicAdd(&sDeg[esrc[ebase + e] - gbase], ew[ebase + e]);
  __syncthreads();
  if (tid < 64) { const float d = sDeg[tid]; sDinv[tid] = (d > 0.f) ? rsqrtf(d) : 0.f; }
  __syncthreads();
  for (int e = tid; e < EPG; e += NTHREADS) {
    const int sl = esrc[ebase + e] - gbase, dl = edst[ebase + e] - gbase;
    atomicAdd(&sLgF[dl * 64 + sl], -(sDinv[sl] * ew[ebase + e] * sDinv[dl]));
  }
  __syncthreads();

  // ---------------- stage M1/M1T ; preload W-frags + bias (Wt dead after) ----------------
  f16x8 Wf[4][2];     // W_k^T B-frags (K32): B[j=f][m=c] = wB[k][c][f]
  f16x8 Wzf;          // Wz B-frag: B[j=f][m<4] = wA[m][f]
  f32x4 bsr;
  for (int idx = tid; idx < 4096; idx += NTHREADS) {
    const int i = idx >> 6, j = idx & 63;
    const f16 v = (f16)sLgF[idx];
    sM1[i * 72 + j] = v;
    sM1T[j * 72 + i] = v;
  }
  {
    const int f = strip * 16 + lrow;
#pragma unroll
    for (int k = 0; k < 4; ++k)
#pragma unroll
      for (int ch = 0; ch < 2; ++ch)
        Wf[k][ch] = *(const f16x8*)(sWt + f * 304 + k * 64 + ch * 32 + lk * 8);
    const f16x4 zw = *(const f16x4*)(sWt + f * 304 + 256);
#pragma unroll
    for (int e = 0; e < 8; ++e) Wzf[e] = (f16)0.f;
    if (lk == 0) { Wzf[0] = zw[0]; Wzf[1] = zw[1]; Wzf[2] = zw[2]; Wzf[3] = zw[3]; }
#pragma unroll
    for (int r = 0; r < 4; ++r) bsr[r] = sBsum[strip * 16 + lk * 4 + r];
  }
  __syncthreads();

  const int rbS = wid >> 1;   // setup MFMA windows: 8 waves x 2 tiles

  // ---------------- W5: M2 (both layouts) + Z1 + Z slot0 ----------------
#pragma unroll
  for (int s = 0; s < 2; ++s) {
    const int cbS = (wid & 1) * 2 + s;
    f32x4 d;
    d = mm64t(sM1T, sM1, rbS, cbS, lrow, lk);     // D[p][q] = Lam^2[q][p]
    {
      const int p0 = rbS * 16 + lk * 4, q = cbS * 16 + lrow;
      f16x4 w;
#pragma unroll
      for (int r = 0; r < 4; ++r) w[r] = (f16)(2.f * d[r] - ((p0 + r) == q ? 1.f : 0.f));
      *(f16x4*)(sM2 + q * 72 + p0) = w;           // M2 row-major
    }
    d = mm64t(sM1, sM1T, rbS, cbS, lrow, lk);     // Lam^2[p][q]
    {
      const int p0 = rbS * 16 + lk * 4, q = cbS * 16 + lrow;
      f16x4 w;
#pragma unroll
      for (int r = 0; r < 4; ++r) w[r] = (f16)(2.f * d[r] - ((p0 + r) == q ? 1.f : 0.f));
      *(f16x4*)(sM2T + q * 72 + p0) = w;          // M2^T
    }
    d = mm64t(sM1, sXT, rbS, cbS, lrow, lk);      // Z1[n=p][t=q]
    {
      const int p0 = rbS * 16 + lk * 4, q = cbS * 16 + lrow;
#pragma unroll
      for (int r = 0; r < 4; ++r) sZt[q * 256 + (p0 + r) * 4 + 1] = (f16)d[r];
    }
  }
  for (int idx = tid; idx < 4096; idx += NTHREADS) {
    const int t = idx >> 6, n = idx & 63;
    sZt[(t * 64 + n) * 4 + 0] = sXT[t * 72 + n];
  }
  __syncthreads();

  // ---------------- W6: M3 + Z2 ----------------
#pragma unroll
  for (int s = 0; s < 2; ++s) {
    const int cbS = (wid & 1) * 2 + s;
    f32x4 d;
    d = mm64t(sM2T, sM1, rbS, cbS, lrow, lk);     // D[p][q] = (Lam M2)[q][p]
    {
      const int p0 = rbS * 16 + lk * 4, q = cbS * 16 + lrow;
      const f16x4 lv = *(const f16x4*)(sM1 + q * 72 + p0);
      f16x4 w;
#pragma unroll
      for (int r = 0; r < 4; ++r) w[r] = (f16)(2.f * d[r] - (float)lv[r]);
      *(f16x4*)(sM3 + q * 72 + p0) = w;           // M3 row-major
    }
    d = mm64t(sM2, sXT, rbS, cbS, lrow, lk);      // Z2[n][t]
    {
      const int p0 = rbS * 16 + lk * 4, q = cbS * 16 + lrow;
#pragma unroll
      for (int r = 0; r < 4; ++r) sZt[q * 256 + (p0 + r) * 4 + 2] = (f16)d[r];
    }
  }
  __syncthreads();

  // ---------------- W7: Z3 ----------------
#pragma unroll
  for (int s = 0; s < 2; ++s) {
    const int cbS = (wid & 1) * 2 + s;
    f32x4 d = mm64t(sM3, sXT, rbS, cbS, lrow, lk);
    const int p0 = rbS * 16 + lk * 4, q = cbS * 16 + lrow;
#pragma unroll
    for (int r = 0; r < 4; ++r) sZt[q * 256 + (p0 + r) * 4 + 3] = (f16)d[r];
  }
  __syncthreads();

  // ---------------- Preload M K16 B-frags (for this wave's 2 out-tiles); zero h bufs ----------------
  // Mg[k-1][jtl][np]: B[j=n][m=n'] = M_k[(lane&15)+jt*16][np*16 + lk*4 + e]
  f16x4 Mg[3][2][4];
#pragma unroll
  for (int k = 0; k < 3; ++k) {
    const f16* Mk = (const f16*)(smem + R_M + k * 9216);
#pragma unroll
    for (int jtl = 0; jtl < 2; ++jtl) {
      const int jt = nhalf * 2 + jtl;
#pragma unroll
      for (int np = 0; np < 4; ++np)
        Mg[k][jtl][np] = *(const f16x4*)(Mk + (lrow + jt * 16) * 72 + np * 16 + lk * 4);
    }
  }
  f16x4 iF;
#pragma unroll
  for (int e = 0; e < 4; ++e) iF[e] = (f16)((lrow == lk * 4 + e) ? 1.f : 0.f);
  for (int idx = tid; idx < 4096; idx += NTHREADS)
    ((int*)(smem + R_H))[idx] = 0;   // both h buffers
  // h'-store address (constant per thread)
  const int stByte = ((lrow) | (((strip * 2 + (lk >> 1)) & 3) << 4)) * 16 + (lk & 1) * 8;
  const int stCh = strip >> 1;
  __syncthreads();

  // ---------------- scan: 64 steps, ONE barrier each, zero mid-step LDS ----------------
#pragma unroll 1
  for (int t = 0; t < NSTEPS; ++t) {
    const char* hb_cur = smem + R_H + (t & 1) * 8192;
    char* hb_nxt = (char*)smem + R_H + ((t & 1) ^ 1) * 8192;

    // stage 1: S_k = h @ W_k (+ z @ Wz into S_0), D-layout [row n, col f-in-strip]
    f16x8 hf[4][2];
#pragma unroll
    for (int nt = 0; nt < 4; ++nt)
#pragma unroll
      for (int ch = 0; ch < 2; ++ch)
        hf[nt][ch] = *(const f16x8*)(hb_cur + ((nt * 2 + ch) * 64 + lane) * 16);

    f16x4 Sf[4][4];   // [k][nt]
#pragma unroll
    for (int nt = 0; nt < 4; ++nt) {
      // k = 0: h W0 + z Wz
      f16x8 az;
      {
        const f16x4 zv = *(const f16x4*)(sZt + (t * 64 + lrow + nt * 16) * 4);
#pragma unroll
        for (int e = 0; e < 8; ++e) az[e] = (f16)0.f;
        if (lk == 0) { az[0] = zv[0]; az[1] = zv[1]; az[2] = zv[2]; az[3] = zv[3]; }
      }
      f32x4 s0 = (f32x4){0.f, 0.f, 0.f, 0.f};
      s0 = mfma16(hf[nt][0], Wf[0][0], s0);
      s0 = mfma16(hf[nt][1], Wf[0][1], s0);
      s0 = mfma16(az, Wzf, s0);
#pragma unroll
      for (int r = 0; r < 4; ++r) Sf[0][nt][r] = (f16)s0[r];
#pragma unroll
      for (int k = 1; k < 4; ++k) {
        f32x4 s = (f32x4){0.f, 0.f, 0.f, 0.f};
        s = mfma16(hf[nt][0], Wf[k][0], s);
        s = mfma16(hf[nt][1], Wf[k][1], s);
#pragma unroll
        for (int r = 0; r < 4; ++r) Sf[k][nt][r] = (f16)s[r];
      }
    }

    // stage 2: pre^T[f strip][n tile jt] = S_0 + sum_k M_k-coupling, all in registers
#pragma unroll
    for (int jtl = 0; jtl < 2; ++jtl) {
      const int jt = nhalf * 2 + jtl;
      f32x4 a1 = bsr;
      a1 = k16(Sf[0][jt], iF, a1);                       // identity pass-through of S_0
#pragma unroll
      for (int np = 0; np < 4; ++np) a1 = k16(Sf[1][np], Mg[0][jtl][np], a1);
      f32x4 a2 = (f32x4){0.f, 0.f, 0.f, 0.f};
#pragma unroll
      for (int np = 0; np < 4; ++np) a2 = k16(Sf[2][np], Mg[1][jtl][np], a2);
#pragma unroll
      for (int np = 0; np < 4; ++np) a2 = k16(Sf[3][np], Mg[2][jtl][np], a2);
      const f32x4 p = a1 + a2;
      f16x4 hv;
#pragma unroll
      for (int r = 0; r < 4; ++r) hv[r] = (f16)(1.f / (1.f + __expf(-p[r])));
      *(f16x4*)(hb_nxt + (jt * 2 + stCh) * 1024 + stByte) = hv;
    }
    __syncthreads();
  }

  // ---------------- Phase 3: GCN x2 + FC + log_softmax (fp32) ----------------
  float* sLgG = (float*)(smem + 0);             // [64][68]
  float* sT1g = (float*)(smem + 17408);         // [64][68]
  float* sT2g = (float*)(smem + 34816);         // [64][68]
  const f16* hF = (const f16*)(smem + R_H);     // final h (buf0, frag-linear)

  for (int idx = tid; idx < 64 * 68; idx += NTHREADS) sLgG[idx] = 0.f;
  if (tid < 64) sDeg[tid] = 0.f;
  for (int idx = tid; idx < 4096; idx += NTHREADS) {
    const int n = idx >> 6, c = idx & 63;
    const f16 v = hF[(((n >> 4) * 2 + (c >> 5)) * 64 + (n & 15) + 16 * ((c >> 3) & 3)) * 8 + (c & 7)];
    sT1g[n * 68 + c] = (float)v;
  }
  if (tid < 4) sLogit[tid] = bfc[tid];
  __syncthreads();
  for (int e = tid; e < EPG; e += NTHREADS)
    atomicAdd(&sDeg[edst[ebase + e] - gbase], ew[ebase + e]);
  __syncthreads();
  if (tid < 64) sDinv[tid] = rsqrtf(sDeg[tid] + 1.f);
  __syncthreads();
  for (int e = tid; e < EPG; e += NTHREADS) {
    const int sl = esrc[ebase + e] - gbase, dl = edst[ebase + e] - gbase;
    atomicAdd(&sLgG[dl * 68 + sl], sDinv[sl] * ew[ebase + e] * sDinv[dl]);
  }
  __syncthreads();
  if (tid < 64) sLgG[tid * 68 + tid] += sDinv[tid] * sDinv[tid];
  __syncthreads();

  const bool isTile = tid < 256;
  const int i4 = ((tid >> 4) & 15) * 4;
  const int j4 = (tid & 15) * 4;

  if (isTile) {                                 // xw1 = h @ w1 -> sT2g
    float m[4][4] = {};
    mm4x4_acc<64>(m, sT1g, 68, i4, w1, 64, j4);
#pragma unroll
    for (int rr = 0; rr < 4; ++rr)
      *(float4*)(sT2g + (i4 + rr) * 68 + j4) = make_float4(m[rr][0], m[rr][1], m[rr][2], m[rr][3]);
  }
  __syncthreads();
  if (isTile) {                                 // z1 = relu(Ag @ xw1 + b1) -> sT1g
    float m[4][4] = {};
    mm4x4_acc<64>(m, sLgG, 68, i4, sT2g, 68, j4);
#pragma unroll
    for (int rr = 0; rr < 4; ++rr) {
      float4 o;
      o.x = fmaxf(m[rr][0] + b1[j4 + 0], 0.f);
      o.y = fmaxf(m[rr][1] + b1[j4 + 1], 0.f);
      o.z = fmaxf(m[rr][2] + b1[j4 + 2], 0.f);
      o.w = fmaxf(m[rr][3] + b1[j4 + 3], 0.f);
      *(float4*)(sT1g + (i4 + rr) * 68 + j4) = o;
    }
  }
  __syncthreads();
  if (isTile && j4 < 32) {                      // xw2 = z1 @ w2 -> sT2g
    float m[4][4] = {};
    mm4x4_acc<64>(m, sT1g, 68, i4, w2, 32, j4);
#pragma unroll
    for (int rr = 0; rr < 4; ++rr)
      *(float4*)(sT2g + (i4 + rr) * 68 + j4) = make_float4(m[rr][0], m[rr][1], m[rr][2], m[rr][3]);
  }
  __syncthreads();
  if (isTile && j4 < 32) {                      // z2 = relu(Ag @ xw2 + b2) -> sT1g
    float m[4][4] = {};
    mm4x4_acc<64>(m, sLgG, 68, i4, sT2g, 68, j4);
#pragma unroll
    for (int rr = 0; rr < 4; ++rr) {
      float4 o;
      o.x = fmaxf(m[rr][0] + b2[j4 + 0], 0.f);
      o.y = fmaxf(m[rr][1] + b2[j4 + 1], 0.f);
      o.z = fmaxf(m[rr][2] + b2[j4 + 2], 0.f);
      o.w = fmaxf(m[rr][3] + b2[j4 + 3], 0.f);
      *(float4*)(sT1g + (i4 + rr) * 68 + j4) = o;
    }
  }
  __syncthreads();

  // FC + log_softmax
  float q0 = 0.f, q1 = 0.f, q2 = 0.f, q3 = 0.f;
  for (int f = tid; f < 2048; f += NTHREADS) {
    const int n = f >> 5, c = f & 31;
    const float v = sT1g[n * 68 + c];
    const float4 wv = *(const float4*)(wfc + f * 4);
    q0 += v * wv.x; q1 += v * wv.y; q2 += v * wv.z; q3 += v * wv.w;
  }
#pragma unroll
  for (int off = 1; off < 64; off <<= 1) {
    q0 += __shfl_xor(q0, off);
    q1 += __shfl_xor(q1, off);
    q2 += __shfl_xor(q2, off);
    q3 += __shfl_xor(q3, off);
  }
  if ((tid & 63) == 0) {
    atomicAdd(&sLogit[0], q0);
    atomicAdd(&sLogit[1], q1);
    atomicAdd(&sLogit[2], q2);
    atomicAdd(&sLogit[3], q3);
  }
  __syncthreads();
  if (tid == 0) {
    const float l0 = sLogit[0], l1 = sLogit[1], l2 = sLogit[2], l3 = sLogit[3];
    const float mx = fmaxf(fmaxf(l0, l1), fmaxf(l2, l3));
    const float s = expf(l0 - mx) + expf(l1 - mx) + expf(l2 - mx) + expf(l3 - mx);
    const float lse = mx + logf(s);
    out[b * 4 + 0] = l0 - lse;
    out[b * 4 + 1] = l1 - lse;
    out[b * 4 + 2] = l2 - lse;
    out[b * 4 + 3] = l3 - lse;
  }
}

extern "C" void kernel_launch(void* const* d_in, const int* in_sizes, int n_in,
                              void* d_out, int out_size, void* d_ws, size_t ws_size,
                              hipStream_t stream) {
  gcrnn_mfma6<<<NBLOCKS, NTHREADS, 0, stream>>>(
      (const float*)d_in[0],   // x
      (const float*)d_in[1],   // edge_weight
      (const float*)d_in[2],   // wA
      (const float*)d_in[3],   // bA
      (const float*)d_in[4],   // wB
      (const float*)d_in[5],   // bB
      (const float*)d_in[6],   // w1
      (const float*)d_in[7],   // b1
      (const float*)d_in[8],   // w2
      (const float*)d_in[9],   // b2
      (const float*)d_in[10],  // wfc
      (const float*)d_in[11],  // bfc
      (const int*)d_in[12],    // edge_src
      (const int*)d_in[13],    // edge_dst
      (float*)d_out);
}

// Round 9
// 127.649 us; speedup vs baseline: 2.7174x; 2.7174x over previous
//
#include <hip/hip_runtime.h>
#include <math.h>

#define NODES 64
#define NSTEPS 64
#define EPG 1024
#define NTHREADS 512
#define NBLOCKS 256

typedef _Float16 f16;
typedef f16 f16x8 __attribute__((ext_vector_type(8)));
typedef f16 f16x4 __attribute__((ext_vector_type(4)));
typedef float f32x4 __attribute__((ext_vector_type(4)));

// ---- LDS regions (byte offsets) ----
#define R_WZ    0        // setup: Wt f16 [64 f][304 K] = 38912 ; scan: Zt f16 [64 t][64 n][4] = 32768 ; ph3 overlay
#define R_M     38912    // M1 @ +0, M2 @ +9216, M3 @ +18432  ([64][72] f16, row-major)
#define R_MT    66560    // M1T @ +0, M2T @ +9216
#define R_H     84992    // h frag-linear, 2 buffers x 8192 B:  [4 nt x 2 ch][64 slot][16 B]
#define R_XT    101376   // X^T [64][72] f16 (setup only)
#define R_LGF   110592   // f32 [64][64] Laplacian scratch
#define R_DEG   126976
#define R_DINV  127232
#define R_BSUM  127488
#define R_LOGIT 127744
#define SMEM_BYTES 128000

__device__ __forceinline__ f32x4 mfma16(f16x8 a, f16x8 b, f32x4 c) {
  return __builtin_amdgcn_mfma_f32_16x16x32_f16(a, b, c, 0, 0, 0);
}
__device__ __forceinline__ f32x4 k16(f16x4 a, f16x4 b, f32x4 c) {
  return __builtin_amdgcn_mfma_f32_16x16x16f16(a, b, c, 0, 0, 0);
}

// setup: D[i][j] = sum_m A[rb*16+i][m] * B[cb*16+j][m], strides 72
__device__ __forceinline__ f32x4 mm64t(const f16* __restrict__ A, const f16* __restrict__ B,
                                       int rb, int cb, int lrow, int lk)
{
  f32x4 d = (f32x4){0.f, 0.f, 0.f, 0.f};
#pragma unroll
  for (int ch = 0; ch < 2; ++ch) {
    const f16x8 a = *(const f16x8*)(A + (rb * 16 + lrow) * 72 + ch * 32 + lk * 8);
    const f16x8 b = *(const f16x8*)(B + (cb * 16 + lrow) * 72 + ch * 32 + lk * 8);
    d = mfma16(a, b, d);
  }
  return d;
}

// fp32 4x4-tile matmul (phase 3)
template<int K>
__device__ __forceinline__ void mm4x4_acc(float acc[4][4],
                                          const float* __restrict__ A, int lda, int arow,
                                          const float* __restrict__ Bm, int ldb, int j4)
{
#pragma unroll 2
  for (int kc = 0; kc < K; kc += 4) {
    float av[4][4];
    float bv[4][4];
#pragma unroll
    for (int rr = 0; rr < 4; ++rr) {
      const float4 t = *(const float4*)(A + (arow + rr) * lda + kc);
      av[rr][0] = t.x; av[rr][1] = t.y; av[rr][2] = t.z; av[rr][3] = t.w;
    }
#pragma unroll
    for (int kk = 0; kk < 4; ++kk) {
      const float4 t = *(const float4*)(Bm + (kc + kk) * ldb + j4);
      bv[kk][0] = t.x; bv[kk][1] = t.y; bv[kk][2] = t.z; bv[kk][3] = t.w;
    }
#pragma unroll
    for (int rr = 0; rr < 4; ++rr)
#pragma unroll
      for (int cc = 0; cc < 4; ++cc) {
        float s = acc[rr][cc];
#pragma unroll
        for (int kk = 0; kk < 4; ++kk) s += av[rr][kk] * bv[kk][cc];
        acc[rr][cc] = s;
      }
  }
}

__global__ __launch_bounds__(NTHREADS, 2)
void gcrnn_mfma7(const float* __restrict__ x,     // [16384][64]
                 const float* __restrict__ ew,    // [262144]
                 const float* __restrict__ wA,    // [4][1][64]
                 const float* __restrict__ bA,    // [64]
                 const float* __restrict__ wB,    // [4][64][64]
                 const float* __restrict__ bB,    // [64]
                 const float* __restrict__ w1,    // [64][64]
                 const float* __restrict__ b1,    // [64]
                 const float* __restrict__ w2,    // [64][32]
                 const float* __restrict__ b2,    // [32]
                 const float* __restrict__ wfc,   // [2048][4]
                 const float* __restrict__ bfc,   // [4]
                 const int* __restrict__ esrc,
                 const int* __restrict__ edst,
                 float* __restrict__ out)         // [256][4]
{
  __shared__ __align__(16) char smem[SMEM_BYTES];

  f16*   sWt   = (f16*)(smem + R_WZ);
  f16*   sZt   = (f16*)(smem + R_WZ);
  f16*   sM1   = (f16*)(smem + R_M);
  f16*   sM2   = (f16*)(smem + R_M + 9216);
  f16*   sM3   = (f16*)(smem + R_M + 18432);
  f16*   sM1T  = (f16*)(smem + R_MT);
  f16*   sM2T  = (f16*)(smem + R_MT + 9216);
  f16*   sXT   = (f16*)(smem + R_XT);
  float* sLgF  = (float*)(smem + R_LGF);
  float* sDeg  = (float*)(smem + R_DEG);
  float* sDinv = (float*)(smem + R_DINV);
  float* sBsum = (float*)(smem + R_BSUM);
  float* sLogit= (float*)(smem + R_LOGIT);

  const int b = blockIdx.x, tid = threadIdx.x;
  const int gbase = b * NODES, ebase = b * EPG;
  const int wid = tid >> 6, lane = tid & 63;
  const int lrow = lane & 15, lk = lane >> 4;
  const int strip = wid & 3;          // f-strip (output feature block)
  const int nhalf = wid >> 2;         // n-half: out-tiles {2*nhalf, 2*nhalf+1}

  // ---------------- Setup stage 1: stage Wt, XT; zero LGF ----------------
  for (int idx = tid; idx < 4096; idx += NTHREADS) sLgF[idx] = 0.f;
  if (tid < 64) { sDeg[tid] = 0.f; sBsum[tid] = bA[tid] + bB[tid]; }
  // Wt [f][K=304]: 0..255 = wB (K=64k+c_in, value wB[k][c_in][f]), 256..259 = wA, 260..303 = 0
  for (int idx = tid; idx < 64 * 260; idx += NTHREADS) {
    const int k = idx >> 6, f = idx & 63;
    const float v = (k < 256) ? wB[(k >> 6) * 4096 + (k & 63) * 64 + f]
                              : wA[(k - 256) * 64 + f];
    sWt[f * 304 + k] = (f16)v;
  }
  for (int idx = tid; idx < 64 * 44; idx += NTHREADS) {
    const int f = idx / 44, j = idx - f * 44;
    sWt[f * 304 + 260 + j] = (f16)0.f;
  }
  // X^T: sXT[t*72+n] = x[gbase+n][t]
  for (int idx = tid; idx < 4096; idx += NTHREADS) {
    const int n = idx >> 6, t = idx & 63;
    sXT[t * 72 + n] = (f16)x[gbase * 64 + idx];
  }
  __syncthreads();

  // ---------------- Laplacian build ----------------
  for (int e = tid; e < EPG; e += NTHREADS)
    atomicAdd(&sDeg[esrc[ebase + e] - gbase], ew[ebase + e]);
  __syncthreads();
  if (tid < 64) { const float d = sDeg[tid]; sDinv[tid] = (d > 0.f) ? rsqrtf(d) : 0.f; }
  __syncthreads();
  for (int e = tid; e < EPG; e += NTHREADS) {
    const int sl = esrc[ebase + e] - gbase, dl = edst[ebase + e] - gbase;
    atomicAdd(&sLgF[dl * 64 + sl], -(sDinv[sl] * ew[ebase + e] * sDinv[dl]));
  }
  __syncthreads();

  // ---------------- stage M1/M1T ; preload W-frags + bias (Wt dead after) ----------------
  f16x8 Wf[4][2];     // W_k^T B-frags (K32): B[j=f][m=c] = wB[k][c][f]
  f16x8 Wzf;          // Wz B-frag: B[j=f][m<4] = wA[m][f]
  f32x4 bsr;
  for (int idx = tid; idx < 4096; idx += NTHREADS) {
    const int i = idx >> 6, j = idx & 63;
    const f16 v = (f16)sLgF[idx];
    sM1[i * 72 + j] = v;
    sM1T[j * 72 + i] = v;
  }
  {
    const int f = strip * 16 + lrow;
#pragma unroll
    for (int k = 0; k < 4; ++k)
#pragma unroll
      for (int ch = 0; ch < 2; ++ch)
        Wf[k][ch] = *(const f16x8*)(sWt + f * 304 + k * 64 + ch * 32 + lk * 8);
    const f16x4 zw = *(const f16x4*)(sWt + f * 304 + 256);
#pragma unroll
    for (int e = 0; e < 8; ++e) Wzf[e] = (f16)0.f;
    if (lk == 0) { Wzf[0] = zw[0]; Wzf[1] = zw[1]; Wzf[2] = zw[2]; Wzf[3] = zw[3]; }
#pragma unroll
    for (int r = 0; r < 4; ++r) bsr[r] = sBsum[strip * 16 + lk * 4 + r];
  }
  __syncthreads();

  const int rbS = wid >> 1;   // setup MFMA windows: 8 waves x 2 tiles

  // ---------------- W5: M2 (both layouts) + Z1 + Z slot0 ----------------
#pragma unroll
  for (int s = 0; s < 2; ++s) {
    const int cbS = (wid & 1) * 2 + s;
    f32x4 d;
    d = mm64t(sM1T, sM1, rbS, cbS, lrow, lk);     // D[p][q] = Lam^2[q][p]
    {
      const int p0 = rbS * 16 + lk * 4, q = cbS * 16 + lrow;
      f16x4 w;
#pragma unroll
      for (int r = 0; r < 4; ++r) w[r] = (f16)(2.f * d[r] - ((p0 + r) == q ? 1.f : 0.f));
      *(f16x4*)(sM2 + q * 72 + p0) = w;           // M2 row-major
    }
    d = mm64t(sM1, sM1T, rbS, cbS, lrow, lk);     // Lam^2[p][q]
    {
      const int p0 = rbS * 16 + lk * 4, q = cbS * 16 + lrow;
      f16x4 w;
#pragma unroll
      for (int r = 0; r < 4; ++r) w[r] = (f16)(2.f * d[r] - ((p0 + r) == q ? 1.f : 0.f));
      *(f16x4*)(sM2T + q * 72 + p0) = w;          // M2^T
    }
    d = mm64t(sM1, sXT, rbS, cbS, lrow, lk);      // Z1[n=p][t=q]
    {
      const int p0 = rbS * 16 + lk * 4, q = cbS * 16 + lrow;
#pragma unroll
      for (int r = 0; r < 4; ++r) sZt[q * 256 + (p0 + r) * 4 + 1] = (f16)d[r];
    }
  }
  for (int idx = tid; idx < 4096; idx += NTHREADS) {
    const int t = idx >> 6, n = idx & 63;
    sZt[(t * 64 + n) * 4 + 0] = sXT[t * 72 + n];
  }
  __syncthreads();

  // ---------------- W6: M3 + Z2 ----------------
#pragma unroll
  for (int s = 0; s < 2; ++s) {
    const int cbS = (wid & 1) * 2 + s;
    f32x4 d;
    d = mm64t(sM2T, sM1, rbS, cbS, lrow, lk);     // D[p][q] = (Lam M2)[q][p]
    {
      const int p0 = rbS * 16 + lk * 4, q = cbS * 16 + lrow;
      const f16x4 lv = *(const f16x4*)(sM1 + q * 72 + p0);
      f16x4 w;
#pragma unroll
      for (int r = 0; r < 4; ++r) w[r] = (f16)(2.f * d[r] - (float)lv[r]);
      *(f16x4*)(sM3 + q * 72 + p0) = w;           // M3 row-major
    }
    d = mm64t(sM2, sXT, rbS, cbS, lrow, lk);      // Z2[n][t]
    {
      const int p0 = rbS * 16 + lk * 4, q = cbS * 16 + lrow;
#pragma unroll
      for (int r = 0; r < 4; ++r) sZt[q * 256 + (p0 + r) * 4 + 2] = (f16)d[r];
    }
  }
  __syncthreads();

  // ---------------- W7: Z3 ----------------
#pragma unroll
  for (int s = 0; s < 2; ++s) {
    const int cbS = (wid & 1) * 2 + s;
    f32x4 d = mm64t(sM3, sXT, rbS, cbS, lrow, lk);
    const int p0 = rbS * 16 + lk * 4, q = cbS * 16 + lrow;
#pragma unroll
    for (int r = 0; r < 4; ++r) sZt[q * 256 + (p0 + r) * 4 + 3] = (f16)d[r];
  }
  __syncthreads();

  // ---------------- Preload M K16 B-frags; zero h bufs ----------------
  // Mg[k-1][jtl][np]: B[j=n][m=n'] = M_k[(lane&15)+jt*16][np*16 + lk*4 + e]
  f16x4 Mg[3][2][4];
#pragma unroll
  for (int k = 0; k < 3; ++k) {
    const f16* Mk = (const f16*)(smem + R_M + k * 9216);
#pragma unroll
    for (int jtl = 0; jtl < 2; ++jtl) {
      const int jt = nhalf * 2 + jtl;
#pragma unroll
      for (int np = 0; np < 4; ++np)
        Mg[k][jtl][np] = *(const f16x4*)(Mk + (lrow + jt * 16) * 72 + np * 16 + lk * 4);
    }
  }
  f16x4 iF;
#pragma unroll
  for (int e = 0; e < 4; ++e) iF[e] = (f16)((lrow == lk * 4 + e) ? 1.f : 0.f);
  for (int idx = tid; idx < 4096; idx += NTHREADS)
    ((int*)(smem + R_H))[idx] = 0;   // both h buffers
  // h'-store address (constant per thread)
  const int stByte = ((lrow) | (((strip * 2 + (lk >> 1)) & 3) << 4)) * 16 + (lk & 1) * 8;
  const int stCh = strip >> 1;
  __syncthreads();

  // ---------------- scan: 64 steps, ONE barrier each, zero mid-step LDS ----------------
#pragma unroll 1
  for (int t = 0; t < NSTEPS; ++t) {
    const char* hb_cur = smem + R_H + (t & 1) * 8192;
    char* hb_nxt = (char*)smem + R_H + ((t & 1) ^ 1) * 8192;

    // stage 1: S_k = h @ W_k (+ z @ Wz into S_0), D-layout [row n, col f-in-strip]
    f16x8 hf[4][2];
#pragma unroll
    for (int nt = 0; nt < 4; ++nt)
#pragma unroll
      for (int ch = 0; ch < 2; ++ch)
        hf[nt][ch] = *(const f16x8*)(hb_cur + ((nt * 2 + ch) * 64 + lane) * 16);

    f16x4 Sf[4][4];   // [k][nt] — ALL accesses statically indexed (rule #20)
#pragma unroll
    for (int nt = 0; nt < 4; ++nt) {
      // k = 0: h W0 + z Wz
      f16x8 az;
      {
        const f16x4 zv = *(const f16x4*)(sZt + (t * 64 + lrow + nt * 16) * 4);
#pragma unroll
        for (int e = 0; e < 8; ++e) az[e] = (f16)0.f;
        if (lk == 0) { az[0] = zv[0]; az[1] = zv[1]; az[2] = zv[2]; az[3] = zv[3]; }
      }
      f32x4 s0 = (f32x4){0.f, 0.f, 0.f, 0.f};
      s0 = mfma16(hf[nt][0], Wf[0][0], s0);
      s0 = mfma16(hf[nt][1], Wf[0][1], s0);
      s0 = mfma16(az, Wzf, s0);
#pragma unroll
      for (int r = 0; r < 4; ++r) Sf[0][nt][r] = (f16)s0[r];
#pragma unroll
      for (int k = 1; k < 4; ++k) {
        f32x4 s = (f32x4){0.f, 0.f, 0.f, 0.f};
        s = mfma16(hf[nt][0], Wf[k][0], s);
        s = mfma16(hf[nt][1], Wf[k][1], s);
#pragma unroll
        for (int r = 0; r < 4; ++r) Sf[k][nt][r] = (f16)s[r];
      }
    }

    // stage 2: pre^T[f strip][n tile jt] = S_0 + sum_k M_k-coupling, all registers.
    // FIX (rule #20): select S_0 tile with STATIC indices + wave-uniform ternary,
    // never Sf[0][runtime].
    const f16x4 s0sel0 = (nhalf == 0) ? Sf[0][0] : Sf[0][2];
    const f16x4 s0sel1 = (nhalf == 0) ? Sf[0][1] : Sf[0][3];
#pragma unroll
    for (int jtl = 0; jtl < 2; ++jtl) {
      const int jt = nhalf * 2 + jtl;
      f32x4 a1 = bsr;
      a1 = k16(jtl == 0 ? s0sel0 : s0sel1, iF, a1);      // identity pass-through of S_0
#pragma unroll
      for (int np = 0; np < 4; ++np) a1 = k16(Sf[1][np], Mg[0][jtl][np], a1);
      f32x4 a2 = (f32x4){0.f, 0.f, 0.f, 0.f};
#pragma unroll
      for (int np = 0; np < 4; ++np) a2 = k16(Sf[2][np], Mg[1][jtl][np], a2);
#pragma unroll
      for (int np = 0; np < 4; ++np) a2 = k16(Sf[3][np], Mg[2][jtl][np], a2);
      const f32x4 p = a1 + a2;
      f16x4 hv;
#pragma unroll
      for (int r = 0; r < 4; ++r) hv[r] = (f16)(1.f / (1.f + __expf(-p[r])));
      *(f16x4*)(hb_nxt + (jt * 2 + stCh) * 1024 + stByte) = hv;
    }
    __syncthreads();
  }

  // ---------------- Phase 3: GCN x2 + FC + log_softmax (fp32) ----------------
  float* sLgG = (float*)(smem + 0);             // [64][68]
  float* sT1g = (float*)(smem + 17408);         // [64][68]
  float* sT2g = (float*)(smem + 34816);         // [64][68]
  const f16* hF = (const f16*)(smem + R_H);     // final h (buf0, frag-linear)

  for (int idx = tid; idx < 64 * 68; idx += NTHREADS) sLgG[idx] = 0.f;
  if (tid < 64) sDeg[tid] = 0.f;
  for (int idx = tid; idx < 4096; idx += NTHREADS) {
    const int n = idx >> 6, c = idx & 63;
    const f16 v = hF[(((n >> 4) * 2 + (c >> 5)) * 64 + (n & 15) + 16 * ((c >> 3) & 3)) * 8 + (c & 7)];
    sT1g[n * 68 + c] = (float)v;
  }
  if (tid < 4) sLogit[tid] = bfc[tid];
  __syncthreads();
  for (int e = tid; e < EPG; e += NTHREADS)
    atomicAdd(&sDeg[edst[ebase + e] - gbase], ew[ebase + e]);
  __syncthreads();
  if (tid < 64) sDinv[tid] = rsqrtf(sDeg[tid] + 1.f);
  __syncthreads();
  for (int e = tid; e < EPG; e += NTHREADS) {
    const int sl = esrc[ebase + e] - gbase, dl = edst[ebase + e] - gbase;
    atomicAdd(&sLgG[dl * 68 + sl], sDinv[sl] * ew[ebase + e] * sDinv[dl]);
  }
  __syncthreads();
  if (tid < 64) sLgG[tid * 68 + tid] += sDinv[tid] * sDinv[tid];
  __syncthreads();

  const bool isTile = tid < 256;
  const int i4 = ((tid >> 4) & 15) * 4;
  const int j4 = (tid & 15) * 4;

  if (isTile) {                                 // xw1 = h @ w1 -> sT2g
    float m[4][4] = {};
    mm4x4_acc<64>(m, sT1g, 68, i4, w1, 64, j4);
#pragma unroll
    for (int rr = 0; rr < 4; ++rr)
      *(float4*)(sT2g + (i4 + rr) * 68 + j4) = make_float4(m[rr][0], m[rr][1], m[rr][2], m[rr][3]);
  }
  __syncthreads();
  if (isTile) {                                 // z1 = relu(Ag @ xw1 + b1) -> sT1g
    float m[4][4] = {};
    mm4x4_acc<64>(m, sLgG, 68, i4, sT2g, 68, j4);
#pragma unroll
    for (int rr = 0; rr < 4; ++rr) {
      float4 o;
      o.x = fmaxf(m[rr][0] + b1[j4 + 0], 0.f);
      o.y = fmaxf(m[rr][1] + b1[j4 + 1], 0.f);
      o.z = fmaxf(m[rr][2] + b1[j4 + 2], 0.f);
      o.w = fmaxf(m[rr][3] + b1[j4 + 3], 0.f);
      *(float4*)(sT1g + (i4 + rr) * 68 + j4) = o;
    }
  }
  __syncthreads();
  if (isTile && j4 < 32) {                      // xw2 = z1 @ w2 -> sT2g
    float m[4][4] = {};
    mm4x4_acc<64>(m, sT1g, 68, i4, w2, 32, j4);
#pragma unroll
    for (int rr = 0; rr < 4; ++rr)
      *(float4*)(sT2g + (i4 + rr) * 68 + j4) = make_float4(m[rr][0], m[rr][1], m[rr][2], m[rr][3]);
  }
  __syncthreads();
  if (isTile && j4 < 32) {                      // z2 = relu(Ag @ xw2 + b2) -> sT1g
    float m[4][4] = {};
    mm4x4_acc<64>(m, sLgG, 68, i4, sT2g, 68, j4);
#pragma unroll
    for (int rr = 0; rr < 4; ++rr) {
      float4 o;
      o.x = fmaxf(m[rr][0] + b2[j4 + 0], 0.f);
      o.y = fmaxf(m[rr][1] + b2[j4 + 1], 0.f);
      o.z = fmaxf(m[rr][2] + b2[j4 + 2], 0.f);
      o.w = fmaxf(m[rr][3] + b2[j4 + 3], 0.f);
      *(float4*)(sT1g + (i4 + rr) * 68 + j4) = o;
    }
  }
  __syncthreads();

  // FC + log_softmax
  float q0 = 0.f, q1 = 0.f, q2 = 0.f, q3 = 0.f;
  for (int f = tid; f < 2048; f += NTHREADS) {
    const int n = f >> 5, c = f & 31;
    const float v = sT1g[n * 68 + c];
    const float4 wv = *(const float4*)(wfc + f * 4);
    q0 += v * wv.x; q1 += v * wv.y; q2 += v * wv.z; q3 += v * wv.w;
  }
#pragma unroll
  for (int off = 1; off < 64; off <<= 1) {
    q0 += __shfl_xor(q0, off);
    q1 += __shfl_xor(q1, off);
    q2 += __shfl_xor(q2, off);
    q3 += __shfl_xor(q3, off);
  }
  if ((tid & 63) == 0) {
    atomicAdd(&sLogit[0], q0);
    atomicAdd(&sLogit[1], q1);
    atomicAdd(&sLogit[2], q2);
    atomicAdd(&sLogit[3], q3);
  }
  __syncthreads();
  if (tid == 0) {
    const float l0 = sLogit[0], l1 = sLogit[1], l2 = sLogit[2], l3 = sLogit[3];
    const float mx = fmaxf(fmaxf(l0, l1), fmaxf(l2, l3));
    const float s = expf(l0 - mx) + expf(l1 - mx) + expf(l2 - mx) + expf(l3 - mx);
    const float lse = mx + logf(s);
    out[b * 4 + 0] = l0 - lse;
    out[b * 4 + 1] = l1 - lse;
    out[b * 4 + 2] = l2 - lse;
    out[b * 4 + 3] = l3 - lse;
  }
}

extern "C" void kernel_launch(void* const* d_in, const int* in_sizes, int n_in,
                              void* d_out, int out_size, void* d_ws, size_t ws_size,
                              hipStream_t stream) {
  gcrnn_mfma7<<<NBLOCKS, NTHREADS, 0, stream>>>(
      (const float*)d_in[0],   // x
      (const float*)d_in[1],   // edge_weight
      (const float*)d_in[2],   // wA
      (const float*)d_in[3],   // bA
      (const float*)d_in[4],   // wB
      (const float*)d_in[5],   // bB
      (const float*)d_in[6],   // w1
      (const float*)d_in[7],   // b1
      (const float*)d_in[8],   // w2
      (const float*)d_in[9],   // b2
      (const float*)d_in[10],  // wfc
      (const float*)d_in[11],  // bfc
      (const int*)d_in[12],    // edge_src
      (const int*)d_in[13],    // edge_dst
      (float*)d_out);
}